// Round 9
// baseline (261.360 us; speedup 1.0000x reference)
//
#include <hip/hip_runtime.h>
#include <math.h>

#define BB 256      // batch
#define IC 1152     // in caps
#define OC 10       // out caps
#define OD 16       // out dim
#define ID 8        // in dim
#define ODOC 160

#define NCHUNK 144      // i-chunks of 8 (uhat)
#define NBG 8           // b residue groups (32 b each)
#define UK_THREADS 320  // 8 il x 40 (o,dq)

// s0 kernel: 64 i-chunks (18 i) x 16 b-groups (16 b) = 1024 blocks
#define S0_NCH 64
#define S0_CI 18
#define S0_NB 16
#define S0_NBQ (BB / S0_NB)     // 16
#define S0_THREADS 640          // 16 bl x 40 odq

#define R_THREADS 1024  // 64 il x 16 slot
#define R_IL 64
#define R_STEPS (IC/R_IL)   // 18

typedef unsigned int   u32;
typedef unsigned short u16;

__device__ __forceinline__ float grp16_sum(float x) {
#pragma unroll
    for (int m = 8; m >= 1; m >>= 1) x += __shfl_xor(x, m, 16);
    return x;
}
// squash over the 16-lane d-group
__device__ __forceinline__ float squash_val(float s) {
    float sq = grp16_sum(s * s);
    return s * (sq / ((1.f + sq) * (sqrtf(sq) + 1e-8f)));
}

__device__ __forceinline__ u32 bf16_rne(float f) {
    u32 x = __float_as_uint(f);
    return (x + 0x7FFFu + ((x >> 16) & 1u)) >> 16;
}
__device__ __forceinline__ u32 pack_bf16x2(float lo, float hi) {
    return bf16_rne(lo) | (bf16_rne(hi) << 16);
}
__device__ __forceinline__ float bf_lo(u32 v) { return __uint_as_float(v << 16); }
__device__ __forceinline__ float bf_hi(u32 v) { return __uint_as_float(v & 0xFFFF0000u); }

// s0 kernel: s0[b,od] = sum_{i,k} W[i,od/16,od%16,k] * u[b,i,k]  (f32, direct
// from inputs). r7 failure fixed: only 18 iterations/thread with a hand-written
// 2-deep register prefetch pipeline (wA/wB, statically indexed) so W loads stay
// in flight; 1024 blocks x 10 waves of TLP; W-chunk XCD-pinned (blockIdx low 3
// bits = chunk%8 -> 737 KB/XCD L2-resident across its 16 b-group blocks).
__global__ void s0_kernel(const float* __restrict__ u,
                          const float* __restrict__ W,
                          float* __restrict__ s0g) {
    __shared__ float ush[S0_NB][S0_CI * ID];   // 16 x 144 = 9.2 KB

    const int t     = threadIdx.x;
    const int chunk = blockIdx.x & (S0_NCH - 1);   // low bits -> XCD-pinned
    const int bq    = blockIdx.x >> 6;
    const int i0    = chunk * S0_CI;
    const int b0    = bq * S0_NB;

    for (int idx = t; idx < S0_NB * S0_CI * ID; idx += S0_THREADS) {
        int bl = idx / (S0_CI * ID), r = idx % (S0_CI * ID);
        ush[bl][r] = u[((size_t)(b0 + bl) * IC + i0) * ID + r];
    }
    __syncthreads();

    const int bl  = t / 40;      // 0..15
    const int odq = t % 40;      // od-quad

    const float4* wp = (const float4*)(W + ((size_t)i0 * ODOC + odq * 4) * ID);
    const int WSTR = ODOC * ID / 4;   // 320 float4 per i-row

    float4 wA[8], wB[8];
#pragma unroll
    for (int q = 0; q < 8; ++q) wA[q] = wp[q];

    float a0 = 0.f, a1 = 0.f, a2 = 0.f, a3 = 0.f;

#pragma unroll
    for (int ii = 0; ii < S0_CI / 2; ++ii) {
        const int ie = ii * 2;
        // prefetch odd iter into wB
#pragma unroll
        for (int q = 0; q < 8; ++q) wB[q] = wp[(ie + 1) * WSTR + q];
        {
            float4 ua = *(const float4*)&ush[bl][ie * ID];
            float4 ub = *(const float4*)&ush[bl][ie * ID + 4];
            a0 += wA[0].x*ua.x + wA[0].y*ua.y + wA[0].z*ua.z + wA[0].w*ua.w
                + wA[1].x*ub.x + wA[1].y*ub.y + wA[1].z*ub.z + wA[1].w*ub.w;
            a1 += wA[2].x*ua.x + wA[2].y*ua.y + wA[2].z*ua.z + wA[2].w*ua.w
                + wA[3].x*ub.x + wA[3].y*ub.y + wA[3].z*ub.z + wA[3].w*ub.w;
            a2 += wA[4].x*ua.x + wA[4].y*ua.y + wA[4].z*ua.z + wA[4].w*ua.w
                + wA[5].x*ub.x + wA[5].y*ub.y + wA[5].z*ub.z + wA[5].w*ub.w;
            a3 += wA[6].x*ua.x + wA[6].y*ua.y + wA[6].z*ua.z + wA[6].w*ua.w
                + wA[7].x*ub.x + wA[7].y*ub.y + wA[7].z*ub.z + wA[7].w*ub.w;
        }
        if (ii + 1 < S0_CI / 2) {   // prefetch next even iter into wA
#pragma unroll
            for (int q = 0; q < 8; ++q) wA[q] = wp[(ie + 2) * WSTR + q];
        }
        {
            float4 ua = *(const float4*)&ush[bl][(ie + 1) * ID];
            float4 ub = *(const float4*)&ush[bl][(ie + 1) * ID + 4];
            a0 += wB[0].x*ua.x + wB[0].y*ua.y + wB[0].z*ua.z + wB[0].w*ua.w
                + wB[1].x*ub.x + wB[1].y*ub.y + wB[1].z*ub.z + wB[1].w*ub.w;
            a1 += wB[2].x*ua.x + wB[2].y*ua.y + wB[2].z*ua.z + wB[2].w*ua.w
                + wB[3].x*ub.x + wB[3].y*ub.y + wB[3].z*ub.z + wB[3].w*ub.w;
            a2 += wB[4].x*ua.x + wB[4].y*ua.y + wB[4].z*ua.z + wB[4].w*ua.w
                + wB[5].x*ub.x + wB[5].y*ub.y + wB[5].z*ub.z + wB[5].w*ub.w;
            a3 += wB[6].x*ua.x + wB[6].y*ua.y + wB[6].z*ua.z + wB[6].w*ua.w
                + wB[7].x*ub.x + wB[7].y*ub.y + wB[7].z*ub.z + wB[7].w*ub.w;
        }
    }

    atomicAdd(&s0g[(size_t)(b0 + bl) * ODOC + odq * 4 + 0], a0);
    atomicAdd(&s0g[(size_t)(b0 + bl) * ODOC + odq * 4 + 1], a1);
    atomicAdd(&s0g[(size_t)(b0 + bl) * ODOC + odq * 4 + 2], a2);
    atomicAdd(&s0g[(size_t)(b0 + bl) * ODOC + odq * 4 + 3], a3);
}

// Kernel 1 (round-3 verbatim — proven ~31 us at the write roofline). PURE:
// no s0, no atomics, no extra LDS — rounds 4/5/8 all showed ANY added work
// destroys the dense lockstep write window.
__global__ __launch_bounds__(UK_THREADS) void uhat_kernel(const float* __restrict__ u,
                                                          const float* __restrict__ W,
                                                          u16* __restrict__ uhat) {
    __shared__ float us[32][8][ID];   // 8 KB

    const int t = threadIdx.x;
    const int chunk = blockIdx.x % NCHUNK;
    const int bg    = blockIdx.x / NCHUNK;    // 0..7
    const int i0 = chunk * 8;

    for (int idx = t; idx < 32 * 8 * ID; idx += UK_THREADS) {
        int bb = idx >> 6, r = idx & 63, il = r >> 3, k = r & 7;
        us[bb][il][k] = u[((size_t)(bb * NBG + bg) * IC + (i0 + il)) * ID + k];
    }
    __syncthreads();

    const int il = t / 40;
    const int r  = t % 40;
    const int o  = r >> 2;
    const int dq = r & 3;
    const int i  = i0 + il;

    float w[4][ID];
    const float* wp = W + (((size_t)i * OC + o) * OD + dq * 4) * ID;
#pragma unroll
    for (int j = 0; j < 4; j++)
#pragma unroll
        for (int k = 0; k < ID; k++) w[j][k] = wp[j * ID + k];

    for (int bb = 0; bb < 32; ++bb) {
        const int b = bb * NBG + bg;
        float a0 = 0.f, a1 = 0.f, a2 = 0.f, a3 = 0.f;
#pragma unroll
        for (int k = 0; k < ID; k++) {
            float uu = us[bb][il][k];
            a0 += w[0][k] * uu;
            a1 += w[1][k] * uu;
            a2 += w[2][k] * uu;
            a3 += w[3][k] * uu;
        }
        uint2 pk = make_uint2(pack_bf16x2(a0, a1), pack_bf16x2(a2, a3));
        *(uint2*)(uhat + ((size_t)b * IC + i) * ODOC + o * OD + dq * 4) = pk;
    }
}

// Routing (r7 verbatim, proven ~28 us): one b per block, 1024 threads =
// 64 i-lanes x 16 slots (slot = o for slot<10). v0 from s0g. Two fused
// passes; logits in registers (Lreg[18], static index via full unroll);
// softmax without max-subtraction (|logit| <~ 12, shift-invariant).
// No LDS/barriers in the step loops.
__global__ __launch_bounds__(R_THREADS, 4) void routing_kernel(const u16* __restrict__ uhat,
                                                               const float* __restrict__ s0g,
                                                               float* __restrict__ out) {
    __shared__ float v_sh[ODOC];
    __shared__ float red[R_IL * ODOC];   // 40 KB

    const int t = threadIdx.x;
    const int b = blockIdx.x;
    const int il   = t >> 4;           // 0..63
    const int slot = t & 15;
    const bool act = slot < OC;

    if (t < ODOC) v_sh[t] = squash_val(s0g[(size_t)b * ODOC + t] * 0.1f);
    __syncthreads();

    const u16* ub = uhat + (size_t)b * IC * ODOC;

    float Lreg[R_STEPS];
#pragma unroll
    for (int j = 0; j < R_STEPS; ++j) Lreg[j] = 0.f;

#pragma unroll 1
    for (int pass = 1; pass <= 2; ++pass) {
        float vr[OD];
#pragma unroll
        for (int q = 0; q < 4; q++) {
            float4 vq = *(const float4*)&v_sh[slot * OD + q * 4];
            vr[q * 4 + 0] = vq.x; vr[q * 4 + 1] = vq.y;
            vr[q * 4 + 2] = vq.z; vr[q * 4 + 3] = vq.w;
        }
        float sp[OD];
#pragma unroll
        for (int d = 0; d < OD; ++d) sp[d] = 0.f;

#pragma unroll
        for (int step = 0; step < R_STEPS; ++step) {
            const int i = step * R_IL + il;
            float uh[OD];
            float e = 0.f;
            if (act) {
                const uint4* p = (const uint4*)(ub + (size_t)i * ODOC + slot * OD);
                uint4 A = p[0], B = p[1];
                uh[0]  = bf_lo(A.x); uh[1]  = bf_hi(A.x);
                uh[2]  = bf_lo(A.y); uh[3]  = bf_hi(A.y);
                uh[4]  = bf_lo(A.z); uh[5]  = bf_hi(A.z);
                uh[6]  = bf_lo(A.w); uh[7]  = bf_hi(A.w);
                uh[8]  = bf_lo(B.x); uh[9]  = bf_hi(B.x);
                uh[10] = bf_lo(B.y); uh[11] = bf_hi(B.y);
                uh[12] = bf_lo(B.z); uh[13] = bf_hi(B.z);
                uh[14] = bf_lo(B.w); uh[15] = bf_hi(B.w);
                float a = 0.f;
#pragma unroll
                for (int d = 0; d < OD; d++) a += uh[d] * vr[d];
                Lreg[step] += a;
                e = __expf(Lreg[step]);   // no max-sub: |logit| <~ 12, safe
            }
            float S = grp16_sum(e);
            float c = e / S;
            if (act) {
#pragma unroll
                for (int d = 0; d < OD; d++) sp[d] += c * uh[d];
            }
        }

        if (act) {
#pragma unroll
            for (int q = 0; q < 4; q++)
                *(float4*)&red[il * ODOC + slot * OD + q * 4] =
                    make_float4(sp[q * 4], sp[q * 4 + 1], sp[q * 4 + 2], sp[q * 4 + 3]);
        }
        __syncthreads();
        float sn = 0.f;
        if (t < ODOC) {
#pragma unroll 8
            for (int j = 0; j < R_IL; j++) sn += red[j * ODOC + t];
        }
        float vn = squash_val(sn);
        __syncthreads();
        if (pass == 1) {
            if (t < ODOC) v_sh[t] = vn;
            __syncthreads();
        } else {
            if (t < ODOC) out[(size_t)b * ODOC + t] = vn;
        }
    }
}

extern "C" void kernel_launch(void* const* d_in, const int* in_sizes, int n_in,
                              void* d_out, int out_size, void* d_ws, size_t ws_size,
                              hipStream_t stream) {
    const float* u = (const float*)d_in[0];
    const float* W = (const float*)d_in[1];
    float* out = (float*)d_out;

    const size_t uhat_bytes = (size_t)BB * IC * ODOC * sizeof(u16);   // 94,371,840
    u16*   uhat = (u16*)d_ws;
    float* s0g  = (float*)((char*)d_ws + uhat_bytes);

    hipMemsetAsync(s0g, 0, (size_t)BB * ODOC * sizeof(float), stream);
    hipLaunchKernelGGL(s0_kernel, dim3(S0_NCH * S0_NBQ), dim3(S0_THREADS), 0, stream,
                       u, W, s0g);
    hipLaunchKernelGGL(uhat_kernel, dim3(NCHUNK * NBG), dim3(UK_THREADS), 0, stream,
                       u, W, uhat);
    hipLaunchKernelGGL(routing_kernel, dim3(BB), dim3(R_THREADS), 0, stream,
                       uhat, s0g, out);
}

// Round 10
// 137.841 us; speedup vs baseline: 1.8961x; 1.8961x over previous
//
#include <hip/hip_runtime.h>
#include <math.h>

#define BB 256      // batch
#define IC 1152     // in caps
#define OC 10       // out caps
#define OD 16       // out dim
#define ID 8        // in dim
#define ODOC 160

#define NCHUNK 144      // i-chunks of 8
#define NBG 8           // b residue groups (32 b each)
#define UK_THREADS 320  // 8 il x 40 (o,dq)

#define PPAD 164        // part row pad (f32) — 16B-aligned, de-collides il groups

#define R_THREADS 1024  // 64 il x 16 slot
#define R_IL 64
#define R_STEPS (IC/R_IL)   // 18

typedef unsigned int   u32;
typedef unsigned short u16;

__device__ __forceinline__ float grp16_sum(float x) {
#pragma unroll
    for (int m = 8; m >= 1; m >>= 1) x += __shfl_xor(x, m, 16);
    return x;
}
// squash over the 16-lane d-group
__device__ __forceinline__ float squash_val(float s) {
    float sq = grp16_sum(s * s);
    return s * (sq / ((1.f + sq) * (sqrtf(sq) + 1e-8f)));
}

__device__ __forceinline__ u32 bf16_rne(float f) {
    u32 x = __float_as_uint(f);
    return (x + 0x7FFFu + ((x >> 16) & 1u)) >> 16;
}
__device__ __forceinline__ u32 pack_bf16x2(float lo, float hi) {
    return bf16_rne(lo) | (bf16_rne(hi) << 16);
}
__device__ __forceinline__ float bf_lo(u32 v) { return __uint_as_float(v << 16); }
__device__ __forceinline__ float bf_hi(u32 v) { return __uint_as_float(v & 0xFFFF0000u); }

// s0 kernel: s0[b,od] = sum_i W[i,od]·u[b,i]  (f32, direct from inputs).
// EXACT uhat schedule (W in 32 regs, u in LDS — the proven no-stall FMA loop)
// with the global store removed; r8's debugged phase-reduce does the i/block
// reduction: 8 phases x 4 b -> part LDS -> barrier -> 8-way il-reduce ->
// 2 atomics/thread. Standalone kernel: no write stream to protect (r8 lesson).
__global__ __launch_bounds__(UK_THREADS) void s0_kernel(const float* __restrict__ u,
                                                        const float* __restrict__ W,
                                                        float* __restrict__ s0g) {
    __shared__ float us[32][8][ID];        // 8 KB
    __shared__ float part[8][4][PPAD];     // 20.5 KB

    const int t = threadIdx.x;
    const int chunk = blockIdx.x % NCHUNK;
    const int bg    = blockIdx.x / NCHUNK;    // 0..7
    const int i0 = chunk * 8;

    for (int idx = t; idx < 32 * 8 * ID; idx += UK_THREADS) {
        int bb = idx >> 6, r = idx & 63, il = r >> 3, k = r & 7;
        us[bb][il][k] = u[((size_t)(bb * NBG + bg) * IC + (i0 + il)) * ID + k];
    }
    __syncthreads();

    const int il = t / 40;
    const int r  = t % 40;
    const int o  = r >> 2;
    const int dq = r & 3;
    const int i  = i0 + il;

    float w[4][ID];
    const float* wp = W + (((size_t)i * OC + o) * OD + dq * 4) * ID;
#pragma unroll
    for (int j = 0; j < 4; j++)
#pragma unroll
        for (int k = 0; k < ID; k++) w[j][k] = wp[j * ID + k];

#pragma unroll 1
    for (int phase = 0; phase < 8; ++phase) {
#pragma unroll
        for (int bi = 0; bi < 4; ++bi) {
            const int bb = phase * 4 + bi;
            float a0 = 0.f, a1 = 0.f, a2 = 0.f, a3 = 0.f;
#pragma unroll
            for (int k = 0; k < ID; k++) {
                float uu = us[bb][il][k];
                a0 += w[0][k] * uu;
                a1 += w[1][k] * uu;
                a2 += w[2][k] * uu;
                a3 += w[3][k] * uu;
            }
            *(float4*)&part[il][bi][r * 4] = make_float4(a0, a1, a2, a3);
        }
        __syncthreads();
        // reduce 4*160=640 outputs over 8 il's; 2 outputs per thread
#pragma unroll
        for (int q = 0; q < 2; ++q) {
            int idx = t * 2 + q;            // 0..639
            int bi = idx / ODOC, od = idx % ODOC;
            float s = 0.f;
#pragma unroll
            for (int j = 0; j < 8; j++) s += part[j][bi][od];
            atomicAdd(&s0g[(size_t)((phase * 4 + bi) * NBG + bg) * ODOC + od], s);
        }
        __syncthreads();   // part reads done before next phase overwrites
    }
}

// Kernel 1 (round-3 verbatim — proven ~31 us at the write roofline). PURE:
// no s0, no atomics, no extra LDS — rounds 4/5/8 all showed ANY added work
// destroys the dense lockstep write window.
__global__ __launch_bounds__(UK_THREADS) void uhat_kernel(const float* __restrict__ u,
                                                          const float* __restrict__ W,
                                                          u16* __restrict__ uhat) {
    __shared__ float us[32][8][ID];   // 8 KB

    const int t = threadIdx.x;
    const int chunk = blockIdx.x % NCHUNK;
    const int bg    = blockIdx.x / NCHUNK;    // 0..7
    const int i0 = chunk * 8;

    for (int idx = t; idx < 32 * 8 * ID; idx += UK_THREADS) {
        int bb = idx >> 6, r = idx & 63, il = r >> 3, k = r & 7;
        us[bb][il][k] = u[((size_t)(bb * NBG + bg) * IC + (i0 + il)) * ID + k];
    }
    __syncthreads();

    const int il = t / 40;
    const int r  = t % 40;
    const int o  = r >> 2;
    const int dq = r & 3;
    const int i  = i0 + il;

    float w[4][ID];
    const float* wp = W + (((size_t)i * OC + o) * OD + dq * 4) * ID;
#pragma unroll
    for (int j = 0; j < 4; j++)
#pragma unroll
        for (int k = 0; k < ID; k++) w[j][k] = wp[j * ID + k];

    for (int bb = 0; bb < 32; ++bb) {
        const int b = bb * NBG + bg;
        float a0 = 0.f, a1 = 0.f, a2 = 0.f, a3 = 0.f;
#pragma unroll
        for (int k = 0; k < ID; k++) {
            float uu = us[bb][il][k];
            a0 += w[0][k] * uu;
            a1 += w[1][k] * uu;
            a2 += w[2][k] * uu;
            a3 += w[3][k] * uu;
        }
        uint2 pk = make_uint2(pack_bf16x2(a0, a1), pack_bf16x2(a2, a3));
        *(uint2*)(uhat + ((size_t)b * IC + i) * ODOC + o * OD + dq * 4) = pk;
    }
}

// Routing (r7 verbatim, proven ~28 us): one b per block, 1024 threads =
// 64 i-lanes x 16 slots (slot = o for slot<10). v0 from s0g. Two fused
// passes; logits in registers (Lreg[18], static index via full unroll);
// softmax without max-subtraction (|logit| <~ 12, shift-invariant).
// No LDS/barriers in the step loops.
__global__ __launch_bounds__(R_THREADS, 4) void routing_kernel(const u16* __restrict__ uhat,
                                                               const float* __restrict__ s0g,
                                                               float* __restrict__ out) {
    __shared__ float v_sh[ODOC];
    __shared__ float red[R_IL * ODOC];   // 40 KB

    const int t = threadIdx.x;
    const int b = blockIdx.x;
    const int il   = t >> 4;           // 0..63
    const int slot = t & 15;
    const bool act = slot < OC;

    if (t < ODOC) v_sh[t] = squash_val(s0g[(size_t)b * ODOC + t] * 0.1f);
    __syncthreads();

    const u16* ub = uhat + (size_t)b * IC * ODOC;

    float Lreg[R_STEPS];
#pragma unroll
    for (int j = 0; j < R_STEPS; ++j) Lreg[j] = 0.f;

#pragma unroll 1
    for (int pass = 1; pass <= 2; ++pass) {
        float vr[OD];
#pragma unroll
        for (int q = 0; q < 4; q++) {
            float4 vq = *(const float4*)&v_sh[slot * OD + q * 4];
            vr[q * 4 + 0] = vq.x; vr[q * 4 + 1] = vq.y;
            vr[q * 4 + 2] = vq.z; vr[q * 4 + 3] = vq.w;
        }
        float sp[OD];
#pragma unroll
        for (int d = 0; d < OD; ++d) sp[d] = 0.f;

#pragma unroll
        for (int step = 0; step < R_STEPS; ++step) {
            const int i = step * R_IL + il;
            float uh[OD];
            float e = 0.f;
            if (act) {
                const uint4* p = (const uint4*)(ub + (size_t)i * ODOC + slot * OD);
                uint4 A = p[0], B = p[1];
                uh[0]  = bf_lo(A.x); uh[1]  = bf_hi(A.x);
                uh[2]  = bf_lo(A.y); uh[3]  = bf_hi(A.y);
                uh[4]  = bf_lo(A.z); uh[5]  = bf_hi(A.z);
                uh[6]  = bf_lo(A.w); uh[7]  = bf_hi(A.w);
                uh[8]  = bf_lo(B.x); uh[9]  = bf_hi(B.x);
                uh[10] = bf_lo(B.y); uh[11] = bf_hi(B.y);
                uh[12] = bf_lo(B.z); uh[13] = bf_hi(B.z);
                uh[14] = bf_lo(B.w); uh[15] = bf_hi(B.w);
                float a = 0.f;
#pragma unroll
                for (int d = 0; d < OD; d++) a += uh[d] * vr[d];
                Lreg[step] += a;
                e = __expf(Lreg[step]);   // no max-sub: |logit| <~ 12, safe
            }
            float S = grp16_sum(e);
            float c = e / S;
            if (act) {
#pragma unroll
                for (int d = 0; d < OD; d++) sp[d] += c * uh[d];
            }
        }

        if (act) {
#pragma unroll
            for (int q = 0; q < 4; q++)
                *(float4*)&red[il * ODOC + slot * OD + q * 4] =
                    make_float4(sp[q * 4], sp[q * 4 + 1], sp[q * 4 + 2], sp[q * 4 + 3]);
        }
        __syncthreads();
        float sn = 0.f;
        if (t < ODOC) {
#pragma unroll 8
            for (int j = 0; j < R_IL; j++) sn += red[j * ODOC + t];
        }
        float vn = squash_val(sn);
        __syncthreads();
        if (pass == 1) {
            if (t < ODOC) v_sh[t] = vn;
            __syncthreads();
        } else {
            if (t < ODOC) out[(size_t)b * ODOC + t] = vn;
        }
    }
}

extern "C" void kernel_launch(void* const* d_in, const int* in_sizes, int n_in,
                              void* d_out, int out_size, void* d_ws, size_t ws_size,
                              hipStream_t stream) {
    const float* u = (const float*)d_in[0];
    const float* W = (const float*)d_in[1];
    float* out = (float*)d_out;

    const size_t uhat_bytes = (size_t)BB * IC * ODOC * sizeof(u16);   // 94,371,840
    u16*   uhat = (u16*)d_ws;
    float* s0g  = (float*)((char*)d_ws + uhat_bytes);

    hipMemsetAsync(s0g, 0, (size_t)BB * ODOC * sizeof(float), stream);
    hipLaunchKernelGGL(s0_kernel, dim3(NCHUNK * NBG), dim3(UK_THREADS), 0, stream,
                       u, W, s0g);
    hipLaunchKernelGGL(uhat_kernel, dim3(NCHUNK * NBG), dim3(UK_THREADS), 0, stream,
                       u, W, uhat);
    hipLaunchKernelGGL(routing_kernel, dim3(BB), dim3(R_THREADS), 0, stream,
                       uhat, s0g, out);
}

// Round 11
// 83.892 us; speedup vs baseline: 3.1154x; 1.6431x over previous
//
#include <hip/hip_runtime.h>
#include <math.h>

#define BB 256      // batch
#define IC 1152     // in caps
#define OC 10       // out caps
#define OD 16       // out dim
#define ID 8        // in dim
#define ODOC 160

#define NCHUNK 144      // i-chunks of 8
#define NBG 8           // b residue groups (32 b each)
#define UK_THREADS 320  // 8 il x 40 (o,dq)

#define R_THREADS 1024  // 64 il x 16 slot
#define R_IL 64
#define R_STEPS (IC/R_IL)   // 18
#define RPITCH 164          // red[] row pitch: 160+4 -> il*164 mod 32 = 4 spreads banks

typedef unsigned int   u32;
typedef unsigned short u16;

__device__ __forceinline__ float grp16_sum(float x) {
#pragma unroll
    for (int m = 8; m >= 1; m >>= 1) x += __shfl_xor(x, m, 16);
    return x;
}
// squash over the 16-lane d-group
__device__ __forceinline__ float squash_val(float s) {
    float sq = grp16_sum(s * s);
    return s * (sq / ((1.f + sq) * (sqrtf(sq) + 1e-8f)));
}

__device__ __forceinline__ u32 bf16_rne(float f) {
    u32 x = __float_as_uint(f);
    return (x + 0x7FFFu + ((x >> 16) & 1u)) >> 16;
}
__device__ __forceinline__ u32 pack_bf16x2(float lo, float hi) {
    return bf16_rne(lo) | (bf16_rne(hi) << 16);
}
__device__ __forceinline__ float bf_lo(u32 v) { return __uint_as_float(v << 16); }
__device__ __forceinline__ float bf_hi(u32 v) { return __uint_as_float(v & 0xFFFF0000u); }

// Kernel 1 (round-3 verbatim — proven ~31 us at the write roofline). PURE:
// no s0, no atomics, no extra LDS — rounds 4/5/8 all showed ANY added work
// destroys the dense lockstep write window (all 1152 blocks write b in
// {8bb..8bb+7} at iter bb: dense monotone 2.5 MB write window).
__global__ __launch_bounds__(UK_THREADS) void uhat_kernel(const float* __restrict__ u,
                                                          const float* __restrict__ W,
                                                          u16* __restrict__ uhat) {
    __shared__ float us[32][8][ID];   // 8 KB

    const int t = threadIdx.x;
    const int chunk = blockIdx.x % NCHUNK;
    const int bg    = blockIdx.x / NCHUNK;    // 0..7
    const int i0 = chunk * 8;

    for (int idx = t; idx < 32 * 8 * ID; idx += UK_THREADS) {
        int bb = idx >> 6, r = idx & 63, il = r >> 3, k = r & 7;
        us[bb][il][k] = u[((size_t)(bb * NBG + bg) * IC + (i0 + il)) * ID + k];
    }
    __syncthreads();

    const int il = t / 40;
    const int r  = t % 40;
    const int o  = r >> 2;
    const int dq = r & 3;
    const int i  = i0 + il;

    float w[4][ID];
    const float* wp = W + (((size_t)i * OC + o) * OD + dq * 4) * ID;
#pragma unroll
    for (int j = 0; j < 4; j++)
#pragma unroll
        for (int k = 0; k < ID; k++) w[j][k] = wp[j * ID + k];

    for (int bb = 0; bb < 32; ++bb) {
        const int b = bb * NBG + bg;
        float a0 = 0.f, a1 = 0.f, a2 = 0.f, a3 = 0.f;
#pragma unroll
        for (int k = 0; k < ID; k++) {
            float uu = us[bb][il][k];
            a0 += w[0][k] * uu;
            a1 += w[1][k] * uu;
            a2 += w[2][k] * uu;
            a3 += w[3][k] * uu;
        }
        uint2 pk = make_uint2(pack_bf16x2(a0, a1), pack_bf16x2(a2, a3));
        *(uint2*)(uhat + ((size_t)b * IC + i) * ODOC + o * OD + dq * 4) = pk;
    }
}

// Routing (round-6 structure, 52.6 us measured, + red[] pitch pad): one b per
// block, 1024 threads = 64 i-lanes x 16 slots.
// Pass 0 (sum-only, v0): ALL 16 slots load — each 320 B row (20 uint4 chunks)
// split: slot s reads chunk s, and chunk 16+s if s<4. Zero idle load lanes.
// Passes 1-2: slots 0-9 own o-columns; logits in registers (Lreg[18], static
// index via full unroll); softmax WITHOUT max-subtraction (|logit| <~ 12,
// shift-invariant => identical result). No LDS/barriers in step loops.
__global__ __launch_bounds__(R_THREADS, 4) void routing_kernel(const u16* __restrict__ uhat,
                                                               float* __restrict__ out) {
    __shared__ float v_sh[ODOC];
    __shared__ float red[R_IL * RPITCH];   // 41 KB (padded pitch)

    const int t = threadIdx.x;
    const int b = blockIdx.x;
    const int il   = t >> 4;           // 0..63
    const int slot = t & 15;
    const bool act = slot < OC;

    const u16* ub = uhat + (size_t)b * IC * ODOC;

    // ---- pass 0: s0 = 0.1 * sum_i uh, all lanes loading ----
    {
        float spA[8], spB[8];
#pragma unroll
        for (int e = 0; e < 8; e++) { spA[e] = 0.f; spB[e] = 0.f; }
#pragma unroll
        for (int step = 0; step < R_STEPS; ++step) {
            const uint4* rp = (const uint4*)(ub + (size_t)(step * R_IL + il) * ODOC);
            uint4 A = rp[slot];
            spA[0] += bf_lo(A.x); spA[1] += bf_hi(A.x);
            spA[2] += bf_lo(A.y); spA[3] += bf_hi(A.y);
            spA[4] += bf_lo(A.z); spA[5] += bf_hi(A.z);
            spA[6] += bf_lo(A.w); spA[7] += bf_hi(A.w);
            if (slot < 4) {
                uint4 Bv = rp[16 + slot];
                spB[0] += bf_lo(Bv.x); spB[1] += bf_hi(Bv.x);
                spB[2] += bf_lo(Bv.y); spB[3] += bf_hi(Bv.y);
                spB[4] += bf_lo(Bv.z); spB[5] += bf_hi(Bv.z);
                spB[6] += bf_lo(Bv.w); spB[7] += bf_hi(Bv.w);
            }
        }
        *(float4*)&red[il * RPITCH + slot * 8]     = make_float4(spA[0], spA[1], spA[2], spA[3]);
        *(float4*)&red[il * RPITCH + slot * 8 + 4] = make_float4(spA[4], spA[5], spA[6], spA[7]);
        if (slot < 4) {
            *(float4*)&red[il * RPITCH + 128 + slot * 8]     = make_float4(spB[0], spB[1], spB[2], spB[3]);
            *(float4*)&red[il * RPITCH + 128 + slot * 8 + 4] = make_float4(spB[4], spB[5], spB[6], spB[7]);
        }
        __syncthreads();
        float s0 = 0.f;
        if (t < ODOC) {
#pragma unroll 8
            for (int j = 0; j < R_IL; j++) s0 += red[j * RPITCH + t];
            s0 *= 0.1f;
        }
        float v0 = squash_val(s0);
        __syncthreads();          // red reads done before pass-1 overwrites
        if (t < ODOC) v_sh[t] = v0;
        __syncthreads();
    }

    float Lreg[R_STEPS];
#pragma unroll
    for (int j = 0; j < R_STEPS; ++j) Lreg[j] = 0.f;

    // ---- passes 1-2 ----
#pragma unroll 1
    for (int pass = 1; pass <= 2; ++pass) {
        float vr[OD];
#pragma unroll
        for (int q = 0; q < 4; q++) {
            float4 vq = *(const float4*)&v_sh[slot * OD + q * 4];
            vr[q * 4 + 0] = vq.x; vr[q * 4 + 1] = vq.y;
            vr[q * 4 + 2] = vq.z; vr[q * 4 + 3] = vq.w;
        }
        float sp[OD];
#pragma unroll
        for (int d = 0; d < OD; ++d) sp[d] = 0.f;

#pragma unroll
        for (int step = 0; step < R_STEPS; ++step) {
            const int i = step * R_IL + il;
            float uh[OD];
            float e = 0.f;
            if (act) {
                const uint4* p = (const uint4*)(ub + (size_t)i * ODOC + slot * OD);
                uint4 A = p[0], B = p[1];
                uh[0]  = bf_lo(A.x); uh[1]  = bf_hi(A.x);
                uh[2]  = bf_lo(A.y); uh[3]  = bf_hi(A.y);
                uh[4]  = bf_lo(A.z); uh[5]  = bf_hi(A.z);
                uh[6]  = bf_lo(A.w); uh[7]  = bf_hi(A.w);
                uh[8]  = bf_lo(B.x); uh[9]  = bf_hi(B.x);
                uh[10] = bf_lo(B.y); uh[11] = bf_hi(B.y);
                uh[12] = bf_lo(B.z); uh[13] = bf_hi(B.z);
                uh[14] = bf_lo(B.w); uh[15] = bf_hi(B.w);
                float a = 0.f;
#pragma unroll
                for (int d = 0; d < OD; d++) a += uh[d] * vr[d];
                Lreg[step] += a;
                e = __expf(Lreg[step]);   // no max-sub: |logit| <~ 12, safe
            }
            float S = grp16_sum(e);
            float c = e / S;
            if (act) {
#pragma unroll
                for (int d = 0; d < OD; d++) sp[d] += c * uh[d];
            }
        }

        if (act) {
#pragma unroll
            for (int q = 0; q < 4; q++)
                *(float4*)&red[il * RPITCH + slot * OD + q * 4] =
                    make_float4(sp[q * 4], sp[q * 4 + 1], sp[q * 4 + 2], sp[q * 4 + 3]);
        }
        __syncthreads();
        float sn = 0.f;
        if (t < ODOC) {
#pragma unroll 8
            for (int j = 0; j < R_IL; j++) sn += red[j * RPITCH + t];
        }
        float vn = squash_val(sn);
        __syncthreads();
        if (pass == 1) {
            if (t < ODOC) v_sh[t] = vn;
            __syncthreads();
        } else {
            if (t < ODOC) out[(size_t)b * ODOC + t] = vn;
        }
    }
}

extern "C" void kernel_launch(void* const* d_in, const int* in_sizes, int n_in,
                              void* d_out, int out_size, void* d_ws, size_t ws_size,
                              hipStream_t stream) {
    const float* u = (const float*)d_in[0];
    const float* W = (const float*)d_in[1];
    float* out = (float*)d_out;

    u16* uhat = (u16*)d_ws;   // 256*1152*160 bf16 = 94.4 MB

    hipLaunchKernelGGL(uhat_kernel, dim3(NCHUNK * NBG), dim3(UK_THREADS), 0, stream,
                       u, W, uhat);
    hipLaunchKernelGGL(routing_kernel, dim3(BB), dim3(R_THREADS), 0, stream,
                       uhat, out);
}